// Round 19
// baseline (17.297 us; speedup 1.0000x reference)
//
#include <hip/hip_runtime.h>

// PBC nonlinear compensation, D-factorized, single-conv-phase:
// R=4 outputs/thread + bf16-packed D + 1024-thread blocks (8 waves/SIMD):
//   O[b,k,i] = E[b,k,i] + sum_m sm(k;m) * E[b,k-m,i]        (Re part stored)
//   sm(k;m)  = sum_n C[m,n] * D_m[k-n]
//   D_m[x]   = sum_j E_j[x] * conj(E_j[x-m]),  D_{-m}[x] = conj(D_m[x+m])
//
// R18 (15.4us) had pipes only ~50% busy -> latency-bound at 4 waves/SIMD
// (grid 512 = 2 blocks/CU x 8 waves). Same 256-output tile, BLK=1024:
// 16 conv groups x 64 threads, 2 blocks/CU x 16 waves = 8 waves/SIMD (max),
// per-wave conv LDS-op path 48 -> ~25. LDS 66.8 KB/block -> still 2/CU.

typedef float v2f __attribute__((ext_vector_type(2)));
typedef float v4f __attribute__((ext_vector_type(4)));

#define S_LEN 16384
#define SOUT  16284          // S - 2*L
#define BLK   1024
#define NOUT  256            // outputs per block
#define NE    356            // staged E samples: [k0, k0+355]
#define NE2   178            // NE/2 (parity-split halves)
#define ND    307            // D tile: x in [k0+25, k0+331]
#define ND_AL 308            // row stride (rows fully written by pair loop)
#define NDP   154            // ND_AL/2 pairs per row

constexpr int LIMS[26] = {25,25,12,8,6,5,4,3,3,2,2,2,2,
                          1,1,1,1,1,1,1,1,1,1,1,1,1};
constexpr int TS[51] = {
      0,  3,  6,  9, 12, 15, 18, 21, 24, 27, 30, 33, 36,
     39, 44, 49, 54, 59, 66, 73, 82, 93,106,123,148,199,
    250,301,326,343,356,367,376,383,390,395,400,405,410,
    413,416,419,422,425,428,431,434,437,440,443,446};

__device__ __forceinline__ uint32_t pack_bf(float re, float im) {
    uint32_t r;
    asm("v_cvt_pk_bf16_f32 %0, %1, %2" : "=v"(r) : "v"(re), "v"(im));
    return r;                      // re -> [15:0], im -> [31:16]
}
__device__ __forceinline__ v2f unpack_bf(uint32_t u) {
    union { uint32_t i; float f; } lo, hi;
    lo.i = u << 16;
    hi.i = u & 0xFFFF0000u;
    return (v2f){lo.f, hi.f};
}

// One m (both signs), four outputs (o0..o0+3), bf16-packed D quads.
template<int M>
__device__ __forceinline__ void convM4(
    const uint32_t* __restrict__ sDm, const v4f* __restrict__ sEp,
    int o0, const float* __restrict__ Cr0, const float* __restrict__ Ci0,
    float4& acc01, float4& acc23)
{
    constexpr int lim = LIMS[M];
    constexpr int tp  = TS[25 + M];
    constexpr int tn  = TS[25 - M];
    constexpr int A   = 25 + lim;

    v2f SxP[4] = {{0.f,0.f},{0.f,0.f},{0.f,0.f},{0.f,0.f}};
    v2f SyP[4] = {{0.f,0.f},{0.f,0.f},{0.f,0.f},{0.f,0.f}};
    v2f SxN[4] = {{0.f,0.f},{0.f,0.f},{0.f,0.f},{0.f,0.f}};
    v2f SyN[4] = {{0.f,0.f},{0.f,0.f},{0.f,0.f},{0.f,0.f}};

#define TAP4(d_, dd)                                                        \
    { _Pragma("unroll")                                                     \
      for (int r = 0; r < 4; ++r) {                                         \
        if (A + r - (d_) >= 0 && A + r - (d_) <= 2*lim) {                   \
            const float cx = Cr0[tp + A + r - (d_)];                        \
            const float cy = Ci0[tp + A + r - (d_)];                        \
            SxP[r] += cx * (dd);  SyP[r] += cy * (dd);                      \
        }                                                                   \
        if (A + M + r - (d_) >= 0 && A + M + r - (d_) <= 2*lim) {           \
            const float cx = Cr0[tn + A + M + r - (d_)];                    \
            const float cy = Ci0[tn + A + M + r - (d_)];                    \
            SxN[r] += cx * (dd);  SyN[r] += cy * (dd);                      \
        }                                                                   \
      } }
#define TAP4P(d_, dd)                                                       \
    { _Pragma("unroll")                                                     \
      for (int r = 0; r < 4; ++r) {                                         \
        if (A + r - (d_) >= 0 && A + r - (d_) <= 2*lim) {                   \
            const float cx = Cr0[tp + A + r - (d_)];                        \
            const float cy = Ci0[tp + A + r - (d_)];                        \
            SxP[r] += cx * (dd);  SyP[r] += cy * (dd);                      \
        }                                                                   \
      } }
#define TAP4N(d_, dd)                                                       \
    { _Pragma("unroll")                                                     \
      for (int r = 0; r < 4; ++r) {                                         \
        if (A + M + r - (d_) >= 0 && A + M + r - (d_) <= 2*lim) {           \
            const float cx = Cr0[tn + A + M + r - (d_)];                    \
            const float cy = Ci0[tn + A + M + r - (d_)];                    \
            SxN[r] += cx * (dd);  SyN[r] += cy * (dd);                      \
        }                                                                   \
      } }
#define QUAD(d0_, TAPM)                                                     \
    {                                                                       \
        uint4 u = *reinterpret_cast<const uint4*>(&sDm[o0 + (d0_)]);        \
        TAPM((d0_) + 0, unpack_bf(u.x))                                     \
        TAPM((d0_) + 1, unpack_bf(u.y))                                     \
        TAPM((d0_) + 2, unpack_bf(u.z))                                     \
        TAPM((d0_) + 3, unpack_bf(u.w))                                     \
    }

    if constexpr (M < 2*lim + 4) {
        // merged window: d in [25-lim, 28+lim+M]
        constexpr int dlo = (25 - lim) & ~3;
        constexpr int dhi = 28 + lim + M;
        constexpr int NQ  = (dhi - dlo) / 4 + 1;
        #pragma unroll
        for (int q = 0; q < NQ; ++q)
            QUAD(dlo + 4*q, TAP4)
    } else {
        {   // +m window: d in [25-lim, 28+lim]
            constexpr int dlo = (25 - lim) & ~3;
            constexpr int dhi = 28 + lim;
            constexpr int NQ  = (dhi - dlo) / 4 + 1;
            #pragma unroll
            for (int q = 0; q < NQ; ++q)
                QUAD(dlo + 4*q, TAP4P)
        }
        {   // -m window: d in [25+M-lim, 28+M+lim]
            constexpr int dlo = (25 + M - lim) & ~3;
            constexpr int dhi = 28 + M + lim;
            constexpr int NQ  = (dhi - dlo) / 4 + 1;
            #pragma unroll
            for (int q = 0; q < NQ; ++q)
                QUAD(dlo + 4*q, TAP4N)
        }
    }
#undef QUAD
#undef TAP4
#undef TAP4P
#undef TAP4N

    // sign combine + E epilogue
    #pragma unroll
    for (int r = 0; r < 4; ++r) {
        const float spr = SxP[r].x - SyP[r].y, spi = SxP[r].y + SyP[r].x;
        const float snr = SxN[r].x + SyN[r].y, sni = SyN[r].x - SxN[r].y;
        const int sp = o0 + 50 + r - M;        // sample of E[s-M]
        const int sn = o0 + 50 + r + M;        // sample of E[s+M]
        v4f ep = sEp[(sp >> 1) + ((sp & 1) ? NE2 : 0)];
        v4f en = sEp[(sn >> 1) + ((sn & 1) ? NE2 : 0)];
        const float c0 = spr*ep.x - spi*ep.y + snr*en.x - sni*en.y;
        const float c1 = spr*ep.z - spi*ep.w + snr*en.z - sni*en.w;
        if      (r == 0) { acc01.x += c0; acc01.y += c1; }
        else if (r == 1) { acc01.z += c0; acc01.w += c1; }
        else if (r == 2) { acc23.x += c0; acc23.y += c1; }
        else             { acc23.z += c0; acc23.w += c1; }
    }
}

// m = 0: real D (f32 tile), out r: j = 50 + r - d, d in [0, 53].
__device__ __forceinline__ void conv04(
    const float* __restrict__ sD0p, const v4f* __restrict__ sEp,
    int o0, const float* __restrict__ Cr0, const float* __restrict__ Ci0,
    float4& acc01, float4& acc23)
{
    v2f s[4] = {{0.f,0.f},{0.f,0.f},{0.f,0.f},{0.f,0.f}};
    #pragma unroll
    for (int q = 0; q < 14; ++q) {
        const int d0 = 4*q;
        v4f w = *reinterpret_cast<const v4f*>(&sD0p[o0 + d0]);
        #pragma unroll
        for (int e = 0; e < 4; ++e) {
            const int d = d0 + e;
            const float dv = (e==0) ? w.x : (e==1) ? w.y : (e==2) ? w.z : w.w;
            #pragma unroll
            for (int r = 0; r < 4; ++r) {
                if (50 + r - d >= 0 && 50 + r - d <= 50) {
                    v2f cv = { Cr0[199 + 50 + r - d], Ci0[199 + 50 + r - d] };
                    s[r] += dv * cv;
                }
            }
        }
    }
    #pragma unroll
    for (int r = 0; r < 4; ++r) {
        const int sp = o0 + 50 + r;
        v4f e = sEp[(sp >> 1) + ((sp & 1) ? NE2 : 0)];
        const float c0 = s[r].x*e.x - s[r].y*e.y;
        const float c1 = s[r].x*e.z - s[r].y*e.w;
        if      (r == 0) { acc01.x += c0; acc01.y += c1; }
        else if (r == 1) { acc01.z += c0; acc01.w += c1; }
        else if (r == 2) { acc23.x += c0; acc23.y += c1; }
        else             { acc23.z += c0; acc23.w += c1; }
    }
}

__global__ __launch_bounds__(BLK, 8) void pbc_kernel(
    const float* __restrict__ Er, const float* __restrict__ Ei,
    const float* __restrict__ Cr, const float* __restrict__ Ci,
    float* __restrict__ out)
{
    __shared__ __align__(16) v4f      sEp[NE];           //  5.7 KB
    __shared__ __align__(16) uint32_t sDbf[25 * ND_AL];  // 30.8 KB bf16-packed
    __shared__ __align__(16) float    sD0[ND_AL];        //  1.2 KB (m=0, f32)
    __shared__ __align__(16) float4   sAcc[15][64][2];   // 30.0 KB partials
    // total 66.8 KB -> 2 blocks/CU (32 waves/CU, 8 waves/SIMD)

    const int b   = blockIdx.y;
    const int k0  = blockIdx.x * NOUT;
    const int tid = threadIdx.x;

    // ---- stage E tile, parity-split ----
    const float* erb = Er + (size_t)b * (S_LEN * 2);
    const float* eib = Ei + (size_t)b * (S_LEN * 2);
    if (tid < NE2) {
        const int i  = tid;
        const int kg = k0 + 2 * i;
        v4f rr = {0.f,0.f,0.f,0.f}, ii = {0.f,0.f,0.f,0.f};
        if (kg < S_LEN) {
            rr = *reinterpret_cast<const v4f*>(erb + 2 * kg);
            ii = *reinterpret_cast<const v4f*>(eib + 2 * kg);
        }
        sEp[i]       = (v4f){rr.x, ii.x, rr.y, ii.y};   // sample kg (even)
        sEp[i + NE2] = (v4f){rr.z, ii.z, rr.w, ii.w};   // sample kg+1 (odd)
    }
    __syncthreads();

    // ---- D tiles: 6 m-chunks x 154 xp, a0/a1 register-resident ----
    const int chunk = tid / NDP;            // 0..6 (chunk 6: 100 idle)
    const int xp    = tid - chunk * NDP;

#define D_ROW(mv)                                                           \
    {                                                                       \
        const int m_  = (mv);                                               \
        const int sb  = 2 * xp + 25 - m_;                                   \
        const int ib0 = (sb >> 1) + (sb & 1) * NE2;                         \
        const int ib1 = ((sb + 1) >> 1) + ((sb + 1) & 1) * NE2;             \
        v4f b0 = sEp[ib0], b1 = sEp[ib1];                                   \
        float gr0 = a0.x*b0.x + a0.y*b0.y + a0.z*b0.z + a0.w*b0.w;          \
        float gi0 = a0.y*b0.x - a0.x*b0.y + a0.w*b0.z - a0.z*b0.w;          \
        float gr1 = a1.x*b1.x + a1.y*b1.y + a1.z*b1.z + a1.w*b1.w;          \
        float gi1 = a1.y*b1.x - a1.x*b1.y + a1.w*b1.z - a1.z*b1.w;          \
        *reinterpret_cast<uint2*>(&sDbf[(m_ - 1) * ND_AL + 2 * xp]) =       \
            make_uint2(pack_bf(gr0, gi0), pack_bf(gr1, gi1));               \
    }

    if (chunk < 6) {
        v4f a0 = sEp[xp + 12 + NE2];        // sample 2xp+25 (odd)
        v4f a1 = sEp[xp + 13];              // sample 2xp+26 (even)
        if (chunk == 0) {
            float d0 = a0.x*a0.x + a0.y*a0.y + a0.z*a0.z + a0.w*a0.w;
            float d1 = a1.x*a1.x + a1.y*a1.y + a1.z*a1.z + a1.w*a1.w;
            *reinterpret_cast<float2*>(&sD0[2 * xp]) = make_float2(d0, d1);
            #pragma unroll
            for (int m = 1; m <= 4; ++m) D_ROW(m)
        } else if (chunk == 1) {
            #pragma unroll
            for (int m = 5; m <= 8; ++m) D_ROW(m)
        } else if (chunk == 2) {
            #pragma unroll
            for (int m = 9; m <= 12; ++m) D_ROW(m)
        } else if (chunk == 3) {
            #pragma unroll
            for (int m = 13; m <= 16; ++m) D_ROW(m)
        } else if (chunk == 4) {
            #pragma unroll
            for (int m = 17; m <= 20; ++m) D_ROW(m)
        } else {
            #pragma unroll
            for (int m = 21; m <= 25; ++m) D_ROW(m)
        }
    }
#undef D_ROW
    __syncthreads();

    // ---- conv: 16 groups x 64 threads x 4 outputs ----
    // LDS-op loads: singles {m1:22, m0:18, m2:16, m3:14, m4:14, m12:14},
    // pairs ~24-26 -> max 26 (was 48 at 8 groups), and 2x the waves.
    const int g  = tid >> 6;            // one wave per group
    const int t  = tid & 63;
    const int o0 = 4 * t;

    float4 acc01 = make_float4(0.f,0.f,0.f,0.f);
    float4 acc23 = make_float4(0.f,0.f,0.f,0.f);
#define DM(mm) (sDbf + ((mm) - 1) * ND_AL)
    if      (g == 0)  { convM4<1>(DM(1), sEp, o0, Cr, Ci, acc01, acc23); }
    else if (g == 1)  { conv04(sD0, sEp, o0, Cr, Ci, acc01, acc23); }
    else if (g == 2)  { convM4<2>(DM(2), sEp, o0, Cr, Ci, acc01, acc23); }
    else if (g == 3)  { convM4<3>(DM(3), sEp, o0, Cr, Ci, acc01, acc23); }
    else if (g == 4)  { convM4<4>(DM(4), sEp, o0, Cr, Ci, acc01, acc23); }
    else if (g == 5)  { convM4<12>(DM(12), sEp, o0, Cr, Ci, acc01, acc23); }
    else if (g == 6)  { convM4<5>(DM(5),  sEp, o0, Cr, Ci, acc01, acc23);
                        convM4<13>(DM(13), sEp, o0, Cr, Ci, acc01, acc23); }
    else if (g == 7)  { convM4<6>(DM(6),  sEp, o0, Cr, Ci, acc01, acc23);
                        convM4<14>(DM(14), sEp, o0, Cr, Ci, acc01, acc23); }
    else if (g == 8)  { convM4<7>(DM(7),  sEp, o0, Cr, Ci, acc01, acc23);
                        convM4<15>(DM(15), sEp, o0, Cr, Ci, acc01, acc23); }
    else if (g == 9)  { convM4<8>(DM(8),  sEp, o0, Cr, Ci, acc01, acc23);
                        convM4<16>(DM(16), sEp, o0, Cr, Ci, acc01, acc23); }
    else if (g == 10) { convM4<9>(DM(9),  sEp, o0, Cr, Ci, acc01, acc23);
                        convM4<17>(DM(17), sEp, o0, Cr, Ci, acc01, acc23); }
    else if (g == 11) { convM4<10>(DM(10), sEp, o0, Cr, Ci, acc01, acc23);
                        convM4<18>(DM(18), sEp, o0, Cr, Ci, acc01, acc23); }
    else if (g == 12) { convM4<11>(DM(11), sEp, o0, Cr, Ci, acc01, acc23);
                        convM4<19>(DM(19), sEp, o0, Cr, Ci, acc01, acc23); }
    else if (g == 13) { convM4<20>(DM(20), sEp, o0, Cr, Ci, acc01, acc23);
                        convM4<21>(DM(21), sEp, o0, Cr, Ci, acc01, acc23); }
    else if (g == 14) { convM4<22>(DM(22), sEp, o0, Cr, Ci, acc01, acc23);
                        convM4<23>(DM(23), sEp, o0, Cr, Ci, acc01, acc23); }
    else              { convM4<24>(DM(24), sEp, o0, Cr, Ci, acc01, acc23);
                        convM4<25>(DM(25), sEp, o0, Cr, Ci, acc01, acc23); }
#undef DM
    if (g > 0) {
        sAcc[g - 1][t][0] = acc01;
        sAcc[g - 1][t][1] = acc23;
    }
    __syncthreads();

    // ---- combine: wave 0 sums 15 partials + own acc, adds E, stores ----
    if (tid < 64) {
        const int tt = tid;
        const int oo = 4 * tt;
        const int ko = k0 + oo;
        if (ko < SOUT) {                  // SOUT % 4 == 0 -> full quad valid
            float4 a01 = acc01, a23 = acc23;
            #pragma unroll
            for (int i = 0; i < 15; ++i) {
                float4 p0 = sAcc[i][tt][0], p1 = sAcc[i][tt][1];
                a01.x += p0.x; a01.y += p0.y; a01.z += p0.z; a01.w += p0.w;
                a23.x += p1.x; a23.y += p1.y; a23.z += p1.z; a23.w += p1.w;
            }
            v4f e0 = sEp[2*tt + 25];          // sample oo+50 (even)
            v4f e1 = sEp[2*tt + 25 + NE2];    // sample oo+51 (odd)
            v4f e2 = sEp[2*tt + 26];          // sample oo+52 (even)
            v4f e3 = sEp[2*tt + 26 + NE2];    // sample oo+53 (odd)
            float4 o0v, o1v;
            o0v.x = e0.x + a01.x;  o0v.y = e0.z + a01.y;   // ko
            o0v.z = e1.x + a01.z;  o0v.w = e1.z + a01.w;   // ko+1
            o1v.x = e2.x + a23.x;  o1v.y = e2.z + a23.y;   // ko+2
            o1v.z = e3.x + a23.z;  o1v.w = e3.z + a23.w;   // ko+3
            float* dst = out + ((size_t)b * SOUT + ko) * 2;
            *reinterpret_cast<float4*>(dst)     = o0v;
            *reinterpret_cast<float4*>(dst + 4) = o1v;
        }
    }
}

extern "C" void kernel_launch(void* const* d_in, const int* in_sizes, int n_in,
                              void* d_out, int out_size, void* d_ws, size_t ws_size,
                              hipStream_t stream) {
    const float* Er = (const float*)d_in[0];
    const float* Ei = (const float*)d_in[1];
    const float* Cr = (const float*)d_in[2];   // [4, 449], row 0 used
    const float* Ci = (const float*)d_in[3];
    float* out = (float*)d_out;                // [8, 16284, 2] float32 (Re)

    dim3 grid((SOUT + NOUT - 1) / NOUT, 8);
    pbc_kernel<<<grid, BLK, 0, stream>>>(Er, Ei, Cr, Ci, out);
}

// Round 20
// 16.026 us; speedup vs baseline: 1.0793x; 1.0793x over previous
//
#include <hip/hip_runtime.h>

// PBC nonlinear compensation, D-factorized, single-conv-phase:
// R=4 outputs/thread + bf16-packed D + LDS-op-balanced groups (R18 base)
// + 2-wave split combine:
//   O[b,k,i] = E[b,k,i] + sum_m sm(k;m) * E[b,k-m,i]        (Re part stored)
//   sm(k;m)  = sum_n C[m,n] * D_m[k-n]
//   D_m[x]   = sum_j E_j[x] * conj(E_j[x-m]),  D_{-m}[x] = conj(D_m[x+m])
//
// R19 lesson: doubling occupancy (16 waves) regressed — conv is issue-bound
// per wave, and reduction overhead scales with group count. Stay at R18's
// 8 groups; the one remaining serialized phase is the combine (wave 0 did
// 14 sAcc + 4 sEp reads). Now all 8 groups store partials and 128 threads
// each combine a half-quad: 8 sAcc + 2 sEp reads, across 2 waves.

typedef float v2f __attribute__((ext_vector_type(2)));
typedef float v4f __attribute__((ext_vector_type(4)));

#define S_LEN 16384
#define SOUT  16284          // S - 2*L
#define BLK   512
#define NOUT  256            // outputs per block
#define NE    356            // staged E samples: [k0, k0+355]
#define NE2   178            // NE/2 (parity-split halves)
#define ND    307            // D tile: x in [k0+25, k0+331]
#define ND_AL 308            // row stride (rows fully written by pair loop)
#define NDP   154            // ND_AL/2 pairs per row

constexpr int LIMS[26] = {25,25,12,8,6,5,4,3,3,2,2,2,2,
                          1,1,1,1,1,1,1,1,1,1,1,1,1};
constexpr int TS[51] = {
      0,  3,  6,  9, 12, 15, 18, 21, 24, 27, 30, 33, 36,
     39, 44, 49, 54, 59, 66, 73, 82, 93,106,123,148,199,
    250,301,326,343,356,367,376,383,390,395,400,405,410,
    413,416,419,422,425,428,431,434,437,440,443,446};

__device__ __forceinline__ uint32_t pack_bf(float re, float im) {
    uint32_t r;
    asm("v_cvt_pk_bf16_f32 %0, %1, %2" : "=v"(r) : "v"(re), "v"(im));
    return r;                      // re -> [15:0], im -> [31:16]
}
__device__ __forceinline__ v2f unpack_bf(uint32_t u) {
    union { uint32_t i; float f; } lo, hi;
    lo.i = u << 16;
    hi.i = u & 0xFFFF0000u;
    return (v2f){lo.f, hi.f};
}

// One m (both signs), four outputs (o0..o0+3), bf16-packed D quads.
template<int M>
__device__ __forceinline__ void convM4(
    const uint32_t* __restrict__ sDm, const v4f* __restrict__ sEp,
    int o0, const float* __restrict__ Cr0, const float* __restrict__ Ci0,
    float4& acc01, float4& acc23)
{
    constexpr int lim = LIMS[M];
    constexpr int tp  = TS[25 + M];
    constexpr int tn  = TS[25 - M];
    constexpr int A   = 25 + lim;

    v2f SxP[4] = {{0.f,0.f},{0.f,0.f},{0.f,0.f},{0.f,0.f}};
    v2f SyP[4] = {{0.f,0.f},{0.f,0.f},{0.f,0.f},{0.f,0.f}};
    v2f SxN[4] = {{0.f,0.f},{0.f,0.f},{0.f,0.f},{0.f,0.f}};
    v2f SyN[4] = {{0.f,0.f},{0.f,0.f},{0.f,0.f},{0.f,0.f}};

#define TAP4(d_, dd)                                                        \
    { _Pragma("unroll")                                                     \
      for (int r = 0; r < 4; ++r) {                                         \
        if (A + r - (d_) >= 0 && A + r - (d_) <= 2*lim) {                   \
            const float cx = Cr0[tp + A + r - (d_)];                        \
            const float cy = Ci0[tp + A + r - (d_)];                        \
            SxP[r] += cx * (dd);  SyP[r] += cy * (dd);                      \
        }                                                                   \
        if (A + M + r - (d_) >= 0 && A + M + r - (d_) <= 2*lim) {           \
            const float cx = Cr0[tn + A + M + r - (d_)];                    \
            const float cy = Ci0[tn + A + M + r - (d_)];                    \
            SxN[r] += cx * (dd);  SyN[r] += cy * (dd);                      \
        }                                                                   \
      } }
#define TAP4P(d_, dd)                                                       \
    { _Pragma("unroll")                                                     \
      for (int r = 0; r < 4; ++r) {                                         \
        if (A + r - (d_) >= 0 && A + r - (d_) <= 2*lim) {                   \
            const float cx = Cr0[tp + A + r - (d_)];                        \
            const float cy = Ci0[tp + A + r - (d_)];                        \
            SxP[r] += cx * (dd);  SyP[r] += cy * (dd);                      \
        }                                                                   \
      } }
#define TAP4N(d_, dd)                                                       \
    { _Pragma("unroll")                                                     \
      for (int r = 0; r < 4; ++r) {                                         \
        if (A + M + r - (d_) >= 0 && A + M + r - (d_) <= 2*lim) {           \
            const float cx = Cr0[tn + A + M + r - (d_)];                    \
            const float cy = Ci0[tn + A + M + r - (d_)];                    \
            SxN[r] += cx * (dd);  SyN[r] += cy * (dd);                      \
        }                                                                   \
      } }
#define QUAD(d0_, TAPM)                                                     \
    {                                                                       \
        uint4 u = *reinterpret_cast<const uint4*>(&sDm[o0 + (d0_)]);        \
        TAPM((d0_) + 0, unpack_bf(u.x))                                     \
        TAPM((d0_) + 1, unpack_bf(u.y))                                     \
        TAPM((d0_) + 2, unpack_bf(u.z))                                     \
        TAPM((d0_) + 3, unpack_bf(u.w))                                     \
    }

    if constexpr (M < 2*lim + 4) {
        // merged window: d in [25-lim, 28+lim+M]
        constexpr int dlo = (25 - lim) & ~3;
        constexpr int dhi = 28 + lim + M;
        constexpr int NQ  = (dhi - dlo) / 4 + 1;
        #pragma unroll
        for (int q = 0; q < NQ; ++q)
            QUAD(dlo + 4*q, TAP4)
    } else {
        {   // +m window: d in [25-lim, 28+lim]
            constexpr int dlo = (25 - lim) & ~3;
            constexpr int dhi = 28 + lim;
            constexpr int NQ  = (dhi - dlo) / 4 + 1;
            #pragma unroll
            for (int q = 0; q < NQ; ++q)
                QUAD(dlo + 4*q, TAP4P)
        }
        {   // -m window: d in [25+M-lim, 28+M+lim]
            constexpr int dlo = (25 + M - lim) & ~3;
            constexpr int dhi = 28 + M + lim;
            constexpr int NQ  = (dhi - dlo) / 4 + 1;
            #pragma unroll
            for (int q = 0; q < NQ; ++q)
                QUAD(dlo + 4*q, TAP4N)
        }
    }
#undef QUAD
#undef TAP4
#undef TAP4P
#undef TAP4N

    // sign combine + E epilogue (consecutive m in a group CSE E reads)
    #pragma unroll
    for (int r = 0; r < 4; ++r) {
        const float spr = SxP[r].x - SyP[r].y, spi = SxP[r].y + SyP[r].x;
        const float snr = SxN[r].x + SyN[r].y, sni = SyN[r].x - SxN[r].y;
        const int sp = o0 + 50 + r - M;        // sample of E[s-M]
        const int sn = o0 + 50 + r + M;        // sample of E[s+M]
        v4f ep = sEp[(sp >> 1) + ((sp & 1) ? NE2 : 0)];
        v4f en = sEp[(sn >> 1) + ((sn & 1) ? NE2 : 0)];
        const float c0 = spr*ep.x - spi*ep.y + snr*en.x - sni*en.y;
        const float c1 = spr*ep.z - spi*ep.w + snr*en.z - sni*en.w;
        if      (r == 0) { acc01.x += c0; acc01.y += c1; }
        else if (r == 1) { acc01.z += c0; acc01.w += c1; }
        else if (r == 2) { acc23.x += c0; acc23.y += c1; }
        else             { acc23.z += c0; acc23.w += c1; }
    }
}

// m = 0: real D (f32 tile), out r: j = 50 + r - d, d in [0, 53].
__device__ __forceinline__ void conv04(
    const float* __restrict__ sD0p, const v4f* __restrict__ sEp,
    int o0, const float* __restrict__ Cr0, const float* __restrict__ Ci0,
    float4& acc01, float4& acc23)
{
    v2f s[4] = {{0.f,0.f},{0.f,0.f},{0.f,0.f},{0.f,0.f}};
    #pragma unroll
    for (int q = 0; q < 14; ++q) {
        const int d0 = 4*q;
        v4f w = *reinterpret_cast<const v4f*>(&sD0p[o0 + d0]);
        #pragma unroll
        for (int e = 0; e < 4; ++e) {
            const int d = d0 + e;
            const float dv = (e==0) ? w.x : (e==1) ? w.y : (e==2) ? w.z : w.w;
            #pragma unroll
            for (int r = 0; r < 4; ++r) {
                if (50 + r - d >= 0 && 50 + r - d <= 50) {
                    v2f cv = { Cr0[199 + 50 + r - d], Ci0[199 + 50 + r - d] };
                    s[r] += dv * cv;
                }
            }
        }
    }
    #pragma unroll
    for (int r = 0; r < 4; ++r) {
        const int sp = o0 + 50 + r;
        v4f e = sEp[(sp >> 1) + ((sp & 1) ? NE2 : 0)];
        const float c0 = s[r].x*e.x - s[r].y*e.y;
        const float c1 = s[r].x*e.z - s[r].y*e.w;
        if      (r == 0) { acc01.x += c0; acc01.y += c1; }
        else if (r == 1) { acc01.z += c0; acc01.w += c1; }
        else if (r == 2) { acc23.x += c0; acc23.y += c1; }
        else             { acc23.z += c0; acc23.w += c1; }
    }
}

__global__ __launch_bounds__(BLK, 4) void pbc_kernel(
    const float* __restrict__ Er, const float* __restrict__ Ei,
    const float* __restrict__ Cr, const float* __restrict__ Ci,
    float* __restrict__ out)
{
    __shared__ __align__(16) v4f      sEp[NE];           //  5.7 KB
    __shared__ __align__(16) uint32_t sDbf[25 * ND_AL];  // 30.8 KB bf16-packed
    __shared__ __align__(16) float    sD0[ND_AL];        //  1.2 KB (m=0, f32)
    __shared__ __align__(16) float4   sAcc[8][64][2];    // 16.0 KB partials

    const int b   = blockIdx.y;
    const int k0  = blockIdx.x * NOUT;
    const int tid = threadIdx.x;

    // ---- stage E tile, parity-split ----
    const float* erb = Er + (size_t)b * (S_LEN * 2);
    const float* eib = Ei + (size_t)b * (S_LEN * 2);
    if (tid < NE2) {
        const int i  = tid;
        const int kg = k0 + 2 * i;
        v4f rr = {0.f,0.f,0.f,0.f}, ii = {0.f,0.f,0.f,0.f};
        if (kg < S_LEN) {
            rr = *reinterpret_cast<const v4f*>(erb + 2 * kg);
            ii = *reinterpret_cast<const v4f*>(eib + 2 * kg);
        }
        sEp[i]       = (v4f){rr.x, ii.x, rr.y, ii.y};   // sample kg (even)
        sEp[i + NE2] = (v4f){rr.z, ii.z, rr.w, ii.w};   // sample kg+1 (odd)
    }
    __syncthreads();

    // ---- D tiles: 3 m-chunks x 154 xp, a0/a1 register-resident,
    //      consecutive m share one b-read (n+1 reads for n rows) ----
    const int chunk = tid / NDP;            // 0..3 (chunk 3: 50 idle threads)
    const int xp    = tid - chunk * NDP;

#define D_ROW(mv)                                                           \
    {                                                                       \
        const int m_  = (mv);                                               \
        const int sb  = 2 * xp + 25 - m_;                                   \
        const int ib0 = (sb >> 1) + (sb & 1) * NE2;                         \
        const int ib1 = ((sb + 1) >> 1) + ((sb + 1) & 1) * NE2;             \
        v4f b0 = sEp[ib0], b1 = sEp[ib1];                                   \
        float gr0 = a0.x*b0.x + a0.y*b0.y + a0.z*b0.z + a0.w*b0.w;          \
        float gi0 = a0.y*b0.x - a0.x*b0.y + a0.w*b0.z - a0.z*b0.w;          \
        float gr1 = a1.x*b1.x + a1.y*b1.y + a1.z*b1.z + a1.w*b1.w;          \
        float gi1 = a1.y*b1.x - a1.x*b1.y + a1.w*b1.z - a1.z*b1.w;          \
        *reinterpret_cast<uint2*>(&sDbf[(m_ - 1) * ND_AL + 2 * xp]) =       \
            make_uint2(pack_bf(gr0, gi0), pack_bf(gr1, gi1));               \
    }

    if (chunk < 3) {
        v4f a0 = sEp[xp + 12 + NE2];        // sample 2xp+25 (odd)
        v4f a1 = sEp[xp + 13];              // sample 2xp+26 (even)
        if (chunk == 0) {
            float d0 = a0.x*a0.x + a0.y*a0.y + a0.z*a0.z + a0.w*a0.w;
            float d1 = a1.x*a1.x + a1.y*a1.y + a1.z*a1.z + a1.w*a1.w;
            *reinterpret_cast<float2*>(&sD0[2 * xp]) = make_float2(d0, d1);
            #pragma unroll
            for (int m = 1; m <= 7; ++m) D_ROW(m)
        } else if (chunk == 1) {
            #pragma unroll
            for (int m = 8; m <= 16; ++m) D_ROW(m)
        } else {
            #pragma unroll
            for (int m = 17; m <= 25; ++m) D_ROW(m)
        }
    }
#undef D_ROW
    __syncthreads();

    // ---- conv: 8 groups x 64 threads x 4 outputs ----
    // LDS-op cost/group (quads + epilogue): {40,44,39,40,40,48,48,48}
    const int g  = tid >> 6;            // one wave per group
    const int t  = tid & 63;
    const int o0 = 4 * t;

    float4 acc01 = make_float4(0.f,0.f,0.f,0.f);
    float4 acc23 = make_float4(0.f,0.f,0.f,0.f);
#define DM(mm) (sDbf + ((mm) - 1) * ND_AL)
    if (g == 0) {
        conv04(sD0, sEp, o0, Cr, Ci, acc01, acc23);
        convM4<1>(DM(1), sEp, o0, Cr, Ci, acc01, acc23);
    } else if (g == 1) {
        convM4<2>(DM(2), sEp, o0, Cr, Ci, acc01, acc23);
        convM4<3>(DM(3), sEp, o0, Cr, Ci, acc01, acc23);
        convM4<4>(DM(4), sEp, o0, Cr, Ci, acc01, acc23);
    } else if (g == 2) {
        convM4<5>(DM(5), sEp, o0, Cr, Ci, acc01, acc23);
        convM4<6>(DM(6), sEp, o0, Cr, Ci, acc01, acc23);
        convM4<7>(DM(7), sEp, o0, Cr, Ci, acc01, acc23);
    } else if (g == 3) {
        convM4<8>(DM(8), sEp, o0, Cr, Ci, acc01, acc23);
        convM4<9>(DM(9), sEp, o0, Cr, Ci, acc01, acc23);
        convM4<10>(DM(10), sEp, o0, Cr, Ci, acc01, acc23);
    } else if (g == 4) {
        convM4<11>(DM(11), sEp, o0, Cr, Ci, acc01, acc23);
        convM4<12>(DM(12), sEp, o0, Cr, Ci, acc01, acc23);
        convM4<13>(DM(13), sEp, o0, Cr, Ci, acc01, acc23);
    } else if (g == 5) {
        convM4<14>(DM(14), sEp, o0, Cr, Ci, acc01, acc23);
        convM4<15>(DM(15), sEp, o0, Cr, Ci, acc01, acc23);
        convM4<16>(DM(16), sEp, o0, Cr, Ci, acc01, acc23);
        convM4<17>(DM(17), sEp, o0, Cr, Ci, acc01, acc23);
    } else if (g == 6) {
        convM4<18>(DM(18), sEp, o0, Cr, Ci, acc01, acc23);
        convM4<19>(DM(19), sEp, o0, Cr, Ci, acc01, acc23);
        convM4<20>(DM(20), sEp, o0, Cr, Ci, acc01, acc23);
        convM4<21>(DM(21), sEp, o0, Cr, Ci, acc01, acc23);
    } else {
        convM4<22>(DM(22), sEp, o0, Cr, Ci, acc01, acc23);
        convM4<23>(DM(23), sEp, o0, Cr, Ci, acc01, acc23);
        convM4<24>(DM(24), sEp, o0, Cr, Ci, acc01, acc23);
        convM4<25>(DM(25), sEp, o0, Cr, Ci, acc01, acc23);
    }
#undef DM
    sAcc[g][t][0] = acc01;
    sAcc[g][t][1] = acc23;
    __syncthreads();

    // ---- combine: 128 threads, each owns a half-quad (2 outputs) ----
    if (tid < 128) {
        const int tt = tid & 63;          // quad index
        const int h  = tid >> 6;          // half: 0 -> outputs r0,r1; 1 -> r2,r3
        const int oo = 4 * tt + 2 * h;
        const int ko = k0 + oo;
        if (ko < SOUT) {                  // SOUT % 4 == 0 -> full quad valid
            float4 a = sAcc[0][tt][h];
            #pragma unroll
            for (int i = 1; i < 8; ++i) {
                float4 p = sAcc[i][tt][h];
                a.x += p.x; a.y += p.y; a.z += p.z; a.w += p.w;
            }
            // outputs oo (even) and oo+1 (odd): sample oo+50 parity = h? no:
            // oo = 4tt+2h is even, oo+50 even; oo+1+50 odd.
            v4f e0 = sEp[(oo + 50) / 2];             // even sample oo+50
            v4f e1 = sEp[(oo + 50) / 2 + NE2];       // odd  sample oo+51
            float4 o;
            o.x = e0.x + a.x;  o.y = e0.z + a.y;     // ko
            o.z = e1.x + a.z;  o.w = e1.z + a.w;     // ko+1
            *reinterpret_cast<float4*>(out + ((size_t)b * SOUT + ko) * 2) = o;
        }
    }
}

extern "C" void kernel_launch(void* const* d_in, const int* in_sizes, int n_in,
                              void* d_out, int out_size, void* d_ws, size_t ws_size,
                              hipStream_t stream) {
    const float* Er = (const float*)d_in[0];
    const float* Ei = (const float*)d_in[1];
    const float* Cr = (const float*)d_in[2];   // [4, 449], row 0 used
    const float* Ci = (const float*)d_in[3];
    float* out = (float*)d_out;                // [8, 16284, 2] float32 (Re)

    dim3 grid((SOUT + NOUT - 1) / NOUT, 8);
    pbc_kernel<<<grid, BLK, 0, stream>>>(Er, Ei, Cr, Ci, out);
}

// Round 21
// 15.355 us; speedup vs baseline: 1.1265x; 1.0437x over previous
//
#include <hip/hip_runtime.h>

// PBC nonlinear compensation, D-factorized, single-conv-phase:
// R=4 outputs/thread + bf16-packed D + LDS-OP-balanced consecutive-m groups
// + register-shared D-compute:  (byte-exact revert to the R18 best, 15.39us)
//   O[b,k,i] = E[b,k,i] + sum_m sm(k;m) * E[b,k-m,i]        (Re part stored)
//   sm(k;m)  = sum_n C[m,n] * D_m[k-n]
//   D_m[x]   = sum_j E_j[x] * conj(E_j[x-m]),  D_{-m}[x] = conj(D_m[x+m])
//
// Ledger: R19 (16 waves) 17.3us, R20 (split combine) 16.0us, R17 (tap
// balance) 19.8us all lost to this structure. Conv LDS-op/wave floor is
// ~48 (208 epilogue reads + ~170 window quads over 8 groups); remaining
// gap to the ~7.5us LDS-pipe floor is intra-wave dependency latency that
// occupancy/topology changes demonstrably do not close.

typedef float v2f __attribute__((ext_vector_type(2)));
typedef float v4f __attribute__((ext_vector_type(4)));

#define S_LEN 16384
#define SOUT  16284          // S - 2*L
#define BLK   512
#define NOUT  256            // outputs per block
#define NE    356            // staged E samples: [k0, k0+355]
#define NE2   178            // NE/2 (parity-split halves)
#define ND    307            // D tile: x in [k0+25, k0+331]
#define ND_AL 308            // row stride (rows fully written by pair loop)
#define NDP   154            // ND_AL/2 pairs per row

constexpr int LIMS[26] = {25,25,12,8,6,5,4,3,3,2,2,2,2,
                          1,1,1,1,1,1,1,1,1,1,1,1,1};
constexpr int TS[51] = {
      0,  3,  6,  9, 12, 15, 18, 21, 24, 27, 30, 33, 36,
     39, 44, 49, 54, 59, 66, 73, 82, 93,106,123,148,199,
    250,301,326,343,356,367,376,383,390,395,400,405,410,
    413,416,419,422,425,428,431,434,437,440,443,446};

__device__ __forceinline__ uint32_t pack_bf(float re, float im) {
    uint32_t r;
    asm("v_cvt_pk_bf16_f32 %0, %1, %2" : "=v"(r) : "v"(re), "v"(im));
    return r;                      // re -> [15:0], im -> [31:16]
}
__device__ __forceinline__ v2f unpack_bf(uint32_t u) {
    union { uint32_t i; float f; } lo, hi;
    lo.i = u << 16;
    hi.i = u & 0xFFFF0000u;
    return (v2f){lo.f, hi.f};
}

// One m (both signs), four outputs (o0..o0+3), bf16-packed D quads.
template<int M>
__device__ __forceinline__ void convM4(
    const uint32_t* __restrict__ sDm, const v4f* __restrict__ sEp,
    int o0, const float* __restrict__ Cr0, const float* __restrict__ Ci0,
    float4& acc01, float4& acc23)
{
    constexpr int lim = LIMS[M];
    constexpr int tp  = TS[25 + M];
    constexpr int tn  = TS[25 - M];
    constexpr int A   = 25 + lim;

    v2f SxP[4] = {{0.f,0.f},{0.f,0.f},{0.f,0.f},{0.f,0.f}};
    v2f SyP[4] = {{0.f,0.f},{0.f,0.f},{0.f,0.f},{0.f,0.f}};
    v2f SxN[4] = {{0.f,0.f},{0.f,0.f},{0.f,0.f},{0.f,0.f}};
    v2f SyN[4] = {{0.f,0.f},{0.f,0.f},{0.f,0.f},{0.f,0.f}};

#define TAP4(d_, dd)                                                        \
    { _Pragma("unroll")                                                     \
      for (int r = 0; r < 4; ++r) {                                         \
        if (A + r - (d_) >= 0 && A + r - (d_) <= 2*lim) {                   \
            const float cx = Cr0[tp + A + r - (d_)];                        \
            const float cy = Ci0[tp + A + r - (d_)];                        \
            SxP[r] += cx * (dd);  SyP[r] += cy * (dd);                      \
        }                                                                   \
        if (A + M + r - (d_) >= 0 && A + M + r - (d_) <= 2*lim) {           \
            const float cx = Cr0[tn + A + M + r - (d_)];                    \
            const float cy = Ci0[tn + A + M + r - (d_)];                    \
            SxN[r] += cx * (dd);  SyN[r] += cy * (dd);                      \
        }                                                                   \
      } }
#define TAP4P(d_, dd)                                                       \
    { _Pragma("unroll")                                                     \
      for (int r = 0; r < 4; ++r) {                                         \
        if (A + r - (d_) >= 0 && A + r - (d_) <= 2*lim) {                   \
            const float cx = Cr0[tp + A + r - (d_)];                        \
            const float cy = Ci0[tp + A + r - (d_)];                        \
            SxP[r] += cx * (dd);  SyP[r] += cy * (dd);                      \
        }                                                                   \
      } }
#define TAP4N(d_, dd)                                                       \
    { _Pragma("unroll")                                                     \
      for (int r = 0; r < 4; ++r) {                                         \
        if (A + M + r - (d_) >= 0 && A + M + r - (d_) <= 2*lim) {           \
            const float cx = Cr0[tn + A + M + r - (d_)];                    \
            const float cy = Ci0[tn + A + M + r - (d_)];                    \
            SxN[r] += cx * (dd);  SyN[r] += cy * (dd);                      \
        }                                                                   \
      } }
#define QUAD(d0_, TAPM)                                                     \
    {                                                                       \
        uint4 u = *reinterpret_cast<const uint4*>(&sDm[o0 + (d0_)]);        \
        TAPM((d0_) + 0, unpack_bf(u.x))                                     \
        TAPM((d0_) + 1, unpack_bf(u.y))                                     \
        TAPM((d0_) + 2, unpack_bf(u.z))                                     \
        TAPM((d0_) + 3, unpack_bf(u.w))                                     \
    }

    if constexpr (M < 2*lim + 4) {
        // merged window: d in [25-lim, 28+lim+M]
        constexpr int dlo = (25 - lim) & ~3;
        constexpr int dhi = 28 + lim + M;
        constexpr int NQ  = (dhi - dlo) / 4 + 1;
        #pragma unroll
        for (int q = 0; q < NQ; ++q)
            QUAD(dlo + 4*q, TAP4)
    } else {
        {   // +m window: d in [25-lim, 28+lim]
            constexpr int dlo = (25 - lim) & ~3;
            constexpr int dhi = 28 + lim;
            constexpr int NQ  = (dhi - dlo) / 4 + 1;
            #pragma unroll
            for (int q = 0; q < NQ; ++q)
                QUAD(dlo + 4*q, TAP4P)
        }
        {   // -m window: d in [25+M-lim, 28+M+lim]
            constexpr int dlo = (25 + M - lim) & ~3;
            constexpr int dhi = 28 + M + lim;
            constexpr int NQ  = (dhi - dlo) / 4 + 1;
            #pragma unroll
            for (int q = 0; q < NQ; ++q)
                QUAD(dlo + 4*q, TAP4N)
        }
    }
#undef QUAD
#undef TAP4
#undef TAP4P
#undef TAP4N

    // sign combine + E epilogue (consecutive m in a group CSE E reads)
    #pragma unroll
    for (int r = 0; r < 4; ++r) {
        const float spr = SxP[r].x - SyP[r].y, spi = SxP[r].y + SyP[r].x;
        const float snr = SxN[r].x + SyN[r].y, sni = SyN[r].x - SxN[r].y;
        const int sp = o0 + 50 + r - M;        // sample of E[s-M]
        const int sn = o0 + 50 + r + M;        // sample of E[s+M]
        v4f ep = sEp[(sp >> 1) + ((sp & 1) ? NE2 : 0)];
        v4f en = sEp[(sn >> 1) + ((sn & 1) ? NE2 : 0)];
        const float c0 = spr*ep.x - spi*ep.y + snr*en.x - sni*en.y;
        const float c1 = spr*ep.z - spi*ep.w + snr*en.z - sni*en.w;
        if      (r == 0) { acc01.x += c0; acc01.y += c1; }
        else if (r == 1) { acc01.z += c0; acc01.w += c1; }
        else if (r == 2) { acc23.x += c0; acc23.y += c1; }
        else             { acc23.z += c0; acc23.w += c1; }
    }
}

// m = 0: real D (f32 tile), out r: j = 50 + r - d, d in [0, 53].
__device__ __forceinline__ void conv04(
    const float* __restrict__ sD0p, const v4f* __restrict__ sEp,
    int o0, const float* __restrict__ Cr0, const float* __restrict__ Ci0,
    float4& acc01, float4& acc23)
{
    v2f s[4] = {{0.f,0.f},{0.f,0.f},{0.f,0.f},{0.f,0.f}};
    #pragma unroll
    for (int q = 0; q < 14; ++q) {
        const int d0 = 4*q;
        v4f w = *reinterpret_cast<const v4f*>(&sD0p[o0 + d0]);
        #pragma unroll
        for (int e = 0; e < 4; ++e) {
            const int d = d0 + e;
            const float dv = (e==0) ? w.x : (e==1) ? w.y : (e==2) ? w.z : w.w;
            #pragma unroll
            for (int r = 0; r < 4; ++r) {
                if (50 + r - d >= 0 && 50 + r - d <= 50) {
                    v2f cv = { Cr0[199 + 50 + r - d], Ci0[199 + 50 + r - d] };
                    s[r] += dv * cv;
                }
            }
        }
    }
    #pragma unroll
    for (int r = 0; r < 4; ++r) {
        const int sp = o0 + 50 + r;
        v4f e = sEp[(sp >> 1) + ((sp & 1) ? NE2 : 0)];
        const float c0 = s[r].x*e.x - s[r].y*e.y;
        const float c1 = s[r].x*e.z - s[r].y*e.w;
        if      (r == 0) { acc01.x += c0; acc01.y += c1; }
        else if (r == 1) { acc01.z += c0; acc01.w += c1; }
        else if (r == 2) { acc23.x += c0; acc23.y += c1; }
        else             { acc23.z += c0; acc23.w += c1; }
    }
}

__global__ __launch_bounds__(BLK, 4) void pbc_kernel(
    const float* __restrict__ Er, const float* __restrict__ Ei,
    const float* __restrict__ Cr, const float* __restrict__ Ci,
    float* __restrict__ out)
{
    __shared__ __align__(16) v4f      sEp[NE];           //  5.7 KB
    __shared__ __align__(16) uint32_t sDbf[25 * ND_AL];  // 30.8 KB bf16-packed
    __shared__ __align__(16) float    sD0[ND_AL];        //  1.2 KB (m=0, f32)
    __shared__ __align__(16) float4   sAcc[7][64][2];    // 14.3 KB partials

    const int b   = blockIdx.y;
    const int k0  = blockIdx.x * NOUT;
    const int tid = threadIdx.x;

    // ---- stage E tile, parity-split ----
    const float* erb = Er + (size_t)b * (S_LEN * 2);
    const float* eib = Ei + (size_t)b * (S_LEN * 2);
    if (tid < NE2) {
        const int i  = tid;
        const int kg = k0 + 2 * i;
        v4f rr = {0.f,0.f,0.f,0.f}, ii = {0.f,0.f,0.f,0.f};
        if (kg < S_LEN) {
            rr = *reinterpret_cast<const v4f*>(erb + 2 * kg);
            ii = *reinterpret_cast<const v4f*>(eib + 2 * kg);
        }
        sEp[i]       = (v4f){rr.x, ii.x, rr.y, ii.y};   // sample kg (even)
        sEp[i + NE2] = (v4f){rr.z, ii.z, rr.w, ii.w};   // sample kg+1 (odd)
    }
    __syncthreads();

    // ---- D tiles: 3 m-chunks x 154 xp, a0/a1 register-resident,
    //      consecutive m share one b-read (n+1 reads for n rows) ----
    const int chunk = tid / NDP;            // 0..3 (chunk 3: 50 idle threads)
    const int xp    = tid - chunk * NDP;

#define D_ROW(mv)                                                           \
    {                                                                       \
        const int m_  = (mv);                                               \
        const int sb  = 2 * xp + 25 - m_;                                   \
        const int ib0 = (sb >> 1) + (sb & 1) * NE2;                         \
        const int ib1 = ((sb + 1) >> 1) + ((sb + 1) & 1) * NE2;             \
        v4f b0 = sEp[ib0], b1 = sEp[ib1];                                   \
        float gr0 = a0.x*b0.x + a0.y*b0.y + a0.z*b0.z + a0.w*b0.w;          \
        float gi0 = a0.y*b0.x - a0.x*b0.y + a0.w*b0.z - a0.z*b0.w;          \
        float gr1 = a1.x*b1.x + a1.y*b1.y + a1.z*b1.z + a1.w*b1.w;          \
        float gi1 = a1.y*b1.x - a1.x*b1.y + a1.w*b1.z - a1.z*b1.w;          \
        *reinterpret_cast<uint2*>(&sDbf[(m_ - 1) * ND_AL + 2 * xp]) =       \
            make_uint2(pack_bf(gr0, gi0), pack_bf(gr1, gi1));               \
    }

    if (chunk < 3) {
        v4f a0 = sEp[xp + 12 + NE2];        // sample 2xp+25 (odd)
        v4f a1 = sEp[xp + 13];              // sample 2xp+26 (even)
        if (chunk == 0) {
            float d0 = a0.x*a0.x + a0.y*a0.y + a0.z*a0.z + a0.w*a0.w;
            float d1 = a1.x*a1.x + a1.y*a1.y + a1.z*a1.z + a1.w*a1.w;
            *reinterpret_cast<float2*>(&sD0[2 * xp]) = make_float2(d0, d1);
            #pragma unroll
            for (int m = 1; m <= 7; ++m) D_ROW(m)
        } else if (chunk == 1) {
            #pragma unroll
            for (int m = 8; m <= 16; ++m) D_ROW(m)
        } else {
            #pragma unroll
            for (int m = 17; m <= 25; ++m) D_ROW(m)
        }
    }
#undef D_ROW
    __syncthreads();

    // ---- conv: 8 groups x 64 threads x 4 outputs ----
    // LDS-op cost/group (quads + epilogue): {40,44,39,40,40,48,48,48}
    const int g  = tid >> 6;            // one wave per group
    const int t  = tid & 63;
    const int o0 = 4 * t;

    float4 acc01 = make_float4(0.f,0.f,0.f,0.f);
    float4 acc23 = make_float4(0.f,0.f,0.f,0.f);
#define DM(mm) (sDbf + ((mm) - 1) * ND_AL)
    if (g == 0) {
        conv04(sD0, sEp, o0, Cr, Ci, acc01, acc23);
        convM4<1>(DM(1), sEp, o0, Cr, Ci, acc01, acc23);
    } else if (g == 1) {
        convM4<2>(DM(2), sEp, o0, Cr, Ci, acc01, acc23);
        convM4<3>(DM(3), sEp, o0, Cr, Ci, acc01, acc23);
        convM4<4>(DM(4), sEp, o0, Cr, Ci, acc01, acc23);
    } else if (g == 2) {
        convM4<5>(DM(5), sEp, o0, Cr, Ci, acc01, acc23);
        convM4<6>(DM(6), sEp, o0, Cr, Ci, acc01, acc23);
        convM4<7>(DM(7), sEp, o0, Cr, Ci, acc01, acc23);
    } else if (g == 3) {
        convM4<8>(DM(8), sEp, o0, Cr, Ci, acc01, acc23);
        convM4<9>(DM(9), sEp, o0, Cr, Ci, acc01, acc23);
        convM4<10>(DM(10), sEp, o0, Cr, Ci, acc01, acc23);
    } else if (g == 4) {
        convM4<11>(DM(11), sEp, o0, Cr, Ci, acc01, acc23);
        convM4<12>(DM(12), sEp, o0, Cr, Ci, acc01, acc23);
        convM4<13>(DM(13), sEp, o0, Cr, Ci, acc01, acc23);
    } else if (g == 5) {
        convM4<14>(DM(14), sEp, o0, Cr, Ci, acc01, acc23);
        convM4<15>(DM(15), sEp, o0, Cr, Ci, acc01, acc23);
        convM4<16>(DM(16), sEp, o0, Cr, Ci, acc01, acc23);
        convM4<17>(DM(17), sEp, o0, Cr, Ci, acc01, acc23);
    } else if (g == 6) {
        convM4<18>(DM(18), sEp, o0, Cr, Ci, acc01, acc23);
        convM4<19>(DM(19), sEp, o0, Cr, Ci, acc01, acc23);
        convM4<20>(DM(20), sEp, o0, Cr, Ci, acc01, acc23);
        convM4<21>(DM(21), sEp, o0, Cr, Ci, acc01, acc23);
    } else {
        convM4<22>(DM(22), sEp, o0, Cr, Ci, acc01, acc23);
        convM4<23>(DM(23), sEp, o0, Cr, Ci, acc01, acc23);
        convM4<24>(DM(24), sEp, o0, Cr, Ci, acc01, acc23);
        convM4<25>(DM(25), sEp, o0, Cr, Ci, acc01, acc23);
    }
#undef DM
    if (g > 0) {
        sAcc[g - 1][t][0] = acc01;
        sAcc[g - 1][t][1] = acc23;
    }
    __syncthreads();

    // ---- combine: wave 0 sums 7 partials + own acc, adds E, stores ----
    if (tid < 64) {
        const int tt = tid;
        const int oo = 4 * tt;
        const int ko = k0 + oo;
        if (ko < SOUT) {                  // SOUT % 4 == 0 -> full quad valid
            float4 a01 = acc01, a23 = acc23;
            #pragma unroll
            for (int i = 0; i < 7; ++i) {
                float4 p0 = sAcc[i][tt][0], p1 = sAcc[i][tt][1];
                a01.x += p0.x; a01.y += p0.y; a01.z += p0.z; a01.w += p0.w;
                a23.x += p1.x; a23.y += p1.y; a23.z += p1.z; a23.w += p1.w;
            }
            v4f e0 = sEp[2*tt + 25];          // sample oo+50 (even)
            v4f e1 = sEp[2*tt + 25 + NE2];    // sample oo+51 (odd)
            v4f e2 = sEp[2*tt + 26];          // sample oo+52 (even)
            v4f e3 = sEp[2*tt + 26 + NE2];    // sample oo+53 (odd)
            float4 o0v, o1v;
            o0v.x = e0.x + a01.x;  o0v.y = e0.z + a01.y;   // ko
            o0v.z = e1.x + a01.z;  o0v.w = e1.z + a01.w;   // ko+1
            o1v.x = e2.x + a23.x;  o1v.y = e2.z + a23.y;   // ko+2
            o1v.z = e3.x + a23.z;  o1v.w = e3.z + a23.w;   // ko+3
            float* dst = out + ((size_t)b * SOUT + ko) * 2;
            *reinterpret_cast<float4*>(dst)     = o0v;
            *reinterpret_cast<float4*>(dst + 4) = o1v;
        }
    }
}

extern "C" void kernel_launch(void* const* d_in, const int* in_sizes, int n_in,
                              void* d_out, int out_size, void* d_ws, size_t ws_size,
                              hipStream_t stream) {
    const float* Er = (const float*)d_in[0];
    const float* Ei = (const float*)d_in[1];
    const float* Cr = (const float*)d_in[2];   // [4, 449], row 0 used
    const float* Ci = (const float*)d_in[3];
    float* out = (float*)d_out;                // [8, 16284, 2] float32 (Re)

    dim3 grid((SOUT + NOUT - 1) / NOUT, 8);
    pbc_kernel<<<grid, BLK, 0, stream>>>(Er, Ei, Cr, Ci, out);
}

// Round 22
// 15.302 us; speedup vs baseline: 1.1304x; 1.0034x over previous
//
#include <hip/hip_runtime.h>

// PBC nonlinear compensation, D-factorized, single-conv-phase:
// R=4 outputs/thread + bf16-packed D + bf16-packed E EPILOGUE (ds_read2_b64):
//   O[b,k,i] = E[b,k,i] + sum_m sm(k;m) * E[b,k-m,i]        (Re part stored)
//   sm(k;m)  = sum_n C[m,n] * D_m[k-n]
//   D_m[x]   = sum_j E_j[x] * conj(E_j[x-m]),  D_{-m}[x] = conj(D_m[x+m])
//
// R18/R21 base (15.35-15.39us, reproduced). The largest remaining conv-phase
// LDS cost is the epilogue: 8 b128 E-reads per m per thread (24-32 of each
// group's ~48 LDS ops). New: sEb[356] = bf16-packed E (uint2 = 4 bf16 both
// modes); the 4 r's read 2+2 ADJACENT parity-half entries -> compiler merges
// into ds_read2_b64. Per-m epilogue 8 -> 4 instr; max group LDS ops ~48->34.
// f32 sEp kept for D-compute + final combine (precision stays there).

typedef float v2f __attribute__((ext_vector_type(2)));
typedef float v4f __attribute__((ext_vector_type(4)));

#define S_LEN 16384
#define SOUT  16284          // S - 2*L
#define BLK   512
#define NOUT  256            // outputs per block
#define NE    356            // staged E samples: [k0, k0+355]
#define NE2   178            // NE/2 (parity-split halves)
#define ND    307            // D tile: x in [k0+25, k0+331]
#define ND_AL 308            // row stride (rows fully written by pair loop)
#define NDP   154            // ND_AL/2 pairs per row

constexpr int LIMS[26] = {25,25,12,8,6,5,4,3,3,2,2,2,2,
                          1,1,1,1,1,1,1,1,1,1,1,1,1};
constexpr int TS[51] = {
      0,  3,  6,  9, 12, 15, 18, 21, 24, 27, 30, 33, 36,
     39, 44, 49, 54, 59, 66, 73, 82, 93,106,123,148,199,
    250,301,326,343,356,367,376,383,390,395,400,405,410,
    413,416,419,422,425,428,431,434,437,440,443,446};

__device__ __forceinline__ uint32_t pack_bf(float re, float im) {
    uint32_t r;
    asm("v_cvt_pk_bf16_f32 %0, %1, %2" : "=v"(r) : "v"(re), "v"(im));
    return r;                      // re -> [15:0], im -> [31:16]
}
__device__ __forceinline__ v2f unpack_bf(uint32_t u) {
    union { uint32_t i; float f; } lo, hi;
    lo.i = u << 16;
    hi.i = u & 0xFFFF0000u;
    return (v2f){lo.f, hi.f};
}

// One m (both signs), four outputs (o0..o0+3), bf16-packed D quads,
// bf16-packed E epilogue.
template<int M>
__device__ __forceinline__ void convM4(
    const uint32_t* __restrict__ sDm, const uint2* __restrict__ sEb,
    int o0, const float* __restrict__ Cr0, const float* __restrict__ Ci0,
    float4& acc01, float4& acc23)
{
    constexpr int lim = LIMS[M];
    constexpr int tp  = TS[25 + M];
    constexpr int tn  = TS[25 - M];
    constexpr int A   = 25 + lim;

    v2f SxP[4] = {{0.f,0.f},{0.f,0.f},{0.f,0.f},{0.f,0.f}};
    v2f SyP[4] = {{0.f,0.f},{0.f,0.f},{0.f,0.f},{0.f,0.f}};
    v2f SxN[4] = {{0.f,0.f},{0.f,0.f},{0.f,0.f},{0.f,0.f}};
    v2f SyN[4] = {{0.f,0.f},{0.f,0.f},{0.f,0.f},{0.f,0.f}};

#define TAP4(d_, dd)                                                        \
    { _Pragma("unroll")                                                     \
      for (int r = 0; r < 4; ++r) {                                         \
        if (A + r - (d_) >= 0 && A + r - (d_) <= 2*lim) {                   \
            const float cx = Cr0[tp + A + r - (d_)];                        \
            const float cy = Ci0[tp + A + r - (d_)];                        \
            SxP[r] += cx * (dd);  SyP[r] += cy * (dd);                      \
        }                                                                   \
        if (A + M + r - (d_) >= 0 && A + M + r - (d_) <= 2*lim) {           \
            const float cx = Cr0[tn + A + M + r - (d_)];                    \
            const float cy = Ci0[tn + A + M + r - (d_)];                    \
            SxN[r] += cx * (dd);  SyN[r] += cy * (dd);                      \
        }                                                                   \
      } }
#define TAP4P(d_, dd)                                                       \
    { _Pragma("unroll")                                                     \
      for (int r = 0; r < 4; ++r) {                                         \
        if (A + r - (d_) >= 0 && A + r - (d_) <= 2*lim) {                   \
            const float cx = Cr0[tp + A + r - (d_)];                        \
            const float cy = Ci0[tp + A + r - (d_)];                        \
            SxP[r] += cx * (dd);  SyP[r] += cy * (dd);                      \
        }                                                                   \
      } }
#define TAP4N(d_, dd)                                                       \
    { _Pragma("unroll")                                                     \
      for (int r = 0; r < 4; ++r) {                                         \
        if (A + M + r - (d_) >= 0 && A + M + r - (d_) <= 2*lim) {           \
            const float cx = Cr0[tn + A + M + r - (d_)];                    \
            const float cy = Ci0[tn + A + M + r - (d_)];                    \
            SxN[r] += cx * (dd);  SyN[r] += cy * (dd);                      \
        }                                                                   \
      } }
#define QUAD(d0_, TAPM)                                                     \
    {                                                                       \
        uint4 u = *reinterpret_cast<const uint4*>(&sDm[o0 + (d0_)]);        \
        TAPM((d0_) + 0, unpack_bf(u.x))                                     \
        TAPM((d0_) + 1, unpack_bf(u.y))                                     \
        TAPM((d0_) + 2, unpack_bf(u.z))                                     \
        TAPM((d0_) + 3, unpack_bf(u.w))                                     \
    }

    if constexpr (M < 2*lim + 4) {
        // merged window: d in [25-lim, 28+lim+M]
        constexpr int dlo = (25 - lim) & ~3;
        constexpr int dhi = 28 + lim + M;
        constexpr int NQ  = (dhi - dlo) / 4 + 1;
        #pragma unroll
        for (int q = 0; q < NQ; ++q)
            QUAD(dlo + 4*q, TAP4)
    } else {
        {   // +m window: d in [25-lim, 28+lim]
            constexpr int dlo = (25 - lim) & ~3;
            constexpr int dhi = 28 + lim;
            constexpr int NQ  = (dhi - dlo) / 4 + 1;
            #pragma unroll
            for (int q = 0; q < NQ; ++q)
                QUAD(dlo + 4*q, TAP4P)
        }
        {   // -m window: d in [25+M-lim, 28+M+lim]
            constexpr int dlo = (25 + M - lim) & ~3;
            constexpr int dhi = 28 + M + lim;
            constexpr int NQ  = (dhi - dlo) / 4 + 1;
            #pragma unroll
            for (int q = 0; q < NQ; ++q)
                QUAD(dlo + 4*q, TAP4N)
        }
    }
#undef QUAD
#undef TAP4
#undef TAP4P
#undef TAP4N

    // sign combine + bf16-E epilogue: per r, one uint2 for E[s-M] and one
    // for E[s+M]; the 4 r's hit 2+2 adjacent entries per parity half ->
    // ds_read2_b64 merge.
    #pragma unroll
    for (int r = 0; r < 4; ++r) {
        const float spr = SxP[r].x - SyP[r].y, spi = SxP[r].y + SyP[r].x;
        const float snr = SxN[r].x + SyN[r].y, sni = SyN[r].x - SxN[r].y;
        const int sp = o0 + 50 + r - M;        // sample of E[s-M]
        const int sn = o0 + 50 + r + M;        // sample of E[s+M]
        uint2 up = sEb[(sp >> 1) + ((sp & 1) ? NE2 : 0)];
        uint2 un = sEb[(sn >> 1) + ((sn & 1) ? NE2 : 0)];
        v2f ep0 = unpack_bf(up.x), ep1 = unpack_bf(up.y);  // modes 0,1
        v2f en0 = unpack_bf(un.x), en1 = unpack_bf(un.y);
        const float c0 = spr*ep0.x - spi*ep0.y + snr*en0.x - sni*en0.y;
        const float c1 = spr*ep1.x - spi*ep1.y + snr*en1.x - sni*en1.y;
        if      (r == 0) { acc01.x += c0; acc01.y += c1; }
        else if (r == 1) { acc01.z += c0; acc01.w += c1; }
        else if (r == 2) { acc23.x += c0; acc23.y += c1; }
        else             { acc23.z += c0; acc23.w += c1; }
    }
}

// m = 0: real D (f32 tile), out r: j = 50 + r - d, d in [0, 53].
__device__ __forceinline__ void conv04(
    const float* __restrict__ sD0p, const uint2* __restrict__ sEb,
    int o0, const float* __restrict__ Cr0, const float* __restrict__ Ci0,
    float4& acc01, float4& acc23)
{
    v2f s[4] = {{0.f,0.f},{0.f,0.f},{0.f,0.f},{0.f,0.f}};
    #pragma unroll
    for (int q = 0; q < 14; ++q) {
        const int d0 = 4*q;
        v4f w = *reinterpret_cast<const v4f*>(&sD0p[o0 + d0]);
        #pragma unroll
        for (int e = 0; e < 4; ++e) {
            const int d = d0 + e;
            const float dv = (e==0) ? w.x : (e==1) ? w.y : (e==2) ? w.z : w.w;
            #pragma unroll
            for (int r = 0; r < 4; ++r) {
                if (50 + r - d >= 0 && 50 + r - d <= 50) {
                    v2f cv = { Cr0[199 + 50 + r - d], Ci0[199 + 50 + r - d] };
                    s[r] += dv * cv;
                }
            }
        }
    }
    #pragma unroll
    for (int r = 0; r < 4; ++r) {
        const int sp = o0 + 50 + r;
        uint2 up = sEb[(sp >> 1) + ((sp & 1) ? NE2 : 0)];
        v2f e0 = unpack_bf(up.x), e1 = unpack_bf(up.y);
        const float c0 = s[r].x*e0.x - s[r].y*e0.y;
        const float c1 = s[r].x*e1.x - s[r].y*e1.y;
        if      (r == 0) { acc01.x += c0; acc01.y += c1; }
        else if (r == 1) { acc01.z += c0; acc01.w += c1; }
        else if (r == 2) { acc23.x += c0; acc23.y += c1; }
        else             { acc23.z += c0; acc23.w += c1; }
    }
}

__global__ __launch_bounds__(BLK, 4) void pbc_kernel(
    const float* __restrict__ Er, const float* __restrict__ Ei,
    const float* __restrict__ Cr, const float* __restrict__ Ci,
    float* __restrict__ out)
{
    __shared__ __align__(16) v4f      sEp[NE];           //  5.7 KB f32
    __shared__ __align__(16) uint2    sEb[NE];           //  2.8 KB bf16 E
    __shared__ __align__(16) uint32_t sDbf[25 * ND_AL];  // 30.8 KB bf16 D
    __shared__ __align__(16) float    sD0[ND_AL];        //  1.2 KB (m=0, f32)
    __shared__ __align__(16) float4   sAcc[7][64][2];    // 14.3 KB partials
    // total 54.8 KB -> 2 blocks/CU

    const int b   = blockIdx.y;
    const int k0  = blockIdx.x * NOUT;
    const int tid = threadIdx.x;

    // ---- stage E tile, parity-split (f32 + bf16-packed copies) ----
    const float* erb = Er + (size_t)b * (S_LEN * 2);
    const float* eib = Ei + (size_t)b * (S_LEN * 2);
    if (tid < NE2) {
        const int i  = tid;
        const int kg = k0 + 2 * i;
        v4f rr = {0.f,0.f,0.f,0.f}, ii = {0.f,0.f,0.f,0.f};
        if (kg < S_LEN) {
            rr = *reinterpret_cast<const v4f*>(erb + 2 * kg);
            ii = *reinterpret_cast<const v4f*>(eib + 2 * kg);
        }
        sEp[i]       = (v4f){rr.x, ii.x, rr.y, ii.y};   // sample kg (even)
        sEp[i + NE2] = (v4f){rr.z, ii.z, rr.w, ii.w};   // sample kg+1 (odd)
        sEb[i]       = make_uint2(pack_bf(rr.x, ii.x), pack_bf(rr.y, ii.y));
        sEb[i + NE2] = make_uint2(pack_bf(rr.z, ii.z), pack_bf(rr.w, ii.w));
    }
    __syncthreads();

    // ---- D tiles: 3 m-chunks x 154 xp, a0/a1 register-resident ----
    const int chunk = tid / NDP;            // 0..3 (chunk 3: 50 idle threads)
    const int xp    = tid - chunk * NDP;

#define D_ROW(mv)                                                           \
    {                                                                       \
        const int m_  = (mv);                                               \
        const int sb  = 2 * xp + 25 - m_;                                   \
        const int ib0 = (sb >> 1) + (sb & 1) * NE2;                         \
        const int ib1 = ((sb + 1) >> 1) + ((sb + 1) & 1) * NE2;             \
        v4f b0 = sEp[ib0], b1 = sEp[ib1];                                   \
        float gr0 = a0.x*b0.x + a0.y*b0.y + a0.z*b0.z + a0.w*b0.w;          \
        float gi0 = a0.y*b0.x - a0.x*b0.y + a0.w*b0.z - a0.z*b0.w;          \
        float gr1 = a1.x*b1.x + a1.y*b1.y + a1.z*b1.z + a1.w*b1.w;          \
        float gi1 = a1.y*b1.x - a1.x*b1.y + a1.w*b1.z - a1.z*b1.w;          \
        *reinterpret_cast<uint2*>(&sDbf[(m_ - 1) * ND_AL + 2 * xp]) =       \
            make_uint2(pack_bf(gr0, gi0), pack_bf(gr1, gi1));               \
    }

    if (chunk < 3) {
        v4f a0 = sEp[xp + 12 + NE2];        // sample 2xp+25 (odd)
        v4f a1 = sEp[xp + 13];              // sample 2xp+26 (even)
        if (chunk == 0) {
            float d0 = a0.x*a0.x + a0.y*a0.y + a0.z*a0.z + a0.w*a0.w;
            float d1 = a1.x*a1.x + a1.y*a1.y + a1.z*a1.z + a1.w*a1.w;
            *reinterpret_cast<float2*>(&sD0[2 * xp]) = make_float2(d0, d1);
            #pragma unroll
            for (int m = 1; m <= 7; ++m) D_ROW(m)
        } else if (chunk == 1) {
            #pragma unroll
            for (int m = 8; m <= 16; ++m) D_ROW(m)
        } else {
            #pragma unroll
            for (int m = 17; m <= 25; ++m) D_ROW(m)
        }
    }
#undef D_ROW
    __syncthreads();

    // ---- conv: 8 groups x 64 threads x 4 outputs ----
    // LDS-op cost/group now ~{32,34,30,30,30,34,34,34} (epilogue halved+)
    const int g  = tid >> 6;            // one wave per group
    const int t  = tid & 63;
    const int o0 = 4 * t;

    float4 acc01 = make_float4(0.f,0.f,0.f,0.f);
    float4 acc23 = make_float4(0.f,0.f,0.f,0.f);
#define DM(mm) (sDbf + ((mm) - 1) * ND_AL)
    if (g == 0) {
        conv04(sD0, sEb, o0, Cr, Ci, acc01, acc23);
        convM4<1>(DM(1), sEb, o0, Cr, Ci, acc01, acc23);
    } else if (g == 1) {
        convM4<2>(DM(2), sEb, o0, Cr, Ci, acc01, acc23);
        convM4<3>(DM(3), sEb, o0, Cr, Ci, acc01, acc23);
        convM4<4>(DM(4), sEb, o0, Cr, Ci, acc01, acc23);
    } else if (g == 2) {
        convM4<5>(DM(5), sEb, o0, Cr, Ci, acc01, acc23);
        convM4<6>(DM(6), sEb, o0, Cr, Ci, acc01, acc23);
        convM4<7>(DM(7), sEb, o0, Cr, Ci, acc01, acc23);
    } else if (g == 3) {
        convM4<8>(DM(8), sEb, o0, Cr, Ci, acc01, acc23);
        convM4<9>(DM(9), sEb, o0, Cr, Ci, acc01, acc23);
        convM4<10>(DM(10), sEb, o0, Cr, Ci, acc01, acc23);
    } else if (g == 4) {
        convM4<11>(DM(11), sEb, o0, Cr, Ci, acc01, acc23);
        convM4<12>(DM(12), sEb, o0, Cr, Ci, acc01, acc23);
        convM4<13>(DM(13), sEb, o0, Cr, Ci, acc01, acc23);
    } else if (g == 5) {
        convM4<14>(DM(14), sEb, o0, Cr, Ci, acc01, acc23);
        convM4<15>(DM(15), sEb, o0, Cr, Ci, acc01, acc23);
        convM4<16>(DM(16), sEb, o0, Cr, Ci, acc01, acc23);
        convM4<17>(DM(17), sEb, o0, Cr, Ci, acc01, acc23);
    } else if (g == 6) {
        convM4<18>(DM(18), sEb, o0, Cr, Ci, acc01, acc23);
        convM4<19>(DM(19), sEb, o0, Cr, Ci, acc01, acc23);
        convM4<20>(DM(20), sEb, o0, Cr, Ci, acc01, acc23);
        convM4<21>(DM(21), sEb, o0, Cr, Ci, acc01, acc23);
    } else {
        convM4<22>(DM(22), sEb, o0, Cr, Ci, acc01, acc23);
        convM4<23>(DM(23), sEb, o0, Cr, Ci, acc01, acc23);
        convM4<24>(DM(24), sEb, o0, Cr, Ci, acc01, acc23);
        convM4<25>(DM(25), sEb, o0, Cr, Ci, acc01, acc23);
    }
#undef DM
    if (g > 0) {
        sAcc[g - 1][t][0] = acc01;
        sAcc[g - 1][t][1] = acc23;
    }
    __syncthreads();

    // ---- combine: wave 0 sums 7 partials + own acc, adds f32 E, stores ----
    if (tid < 64) {
        const int tt = tid;
        const int oo = 4 * tt;
        const int ko = k0 + oo;
        if (ko < SOUT) {                  // SOUT % 4 == 0 -> full quad valid
            float4 a01 = acc01, a23 = acc23;
            #pragma unroll
            for (int i = 0; i < 7; ++i) {
                float4 p0 = sAcc[i][tt][0], p1 = sAcc[i][tt][1];
                a01.x += p0.x; a01.y += p0.y; a01.z += p0.z; a01.w += p0.w;
                a23.x += p1.x; a23.y += p1.y; a23.z += p1.z; a23.w += p1.w;
            }
            v4f e0 = sEp[2*tt + 25];          // sample oo+50 (even)
            v4f e1 = sEp[2*tt + 25 + NE2];    // sample oo+51 (odd)
            v4f e2 = sEp[2*tt + 26];          // sample oo+52 (even)
            v4f e3 = sEp[2*tt + 26 + NE2];    // sample oo+53 (odd)
            float4 o0v, o1v;
            o0v.x = e0.x + a01.x;  o0v.y = e0.z + a01.y;   // ko
            o0v.z = e1.x + a01.z;  o0v.w = e1.z + a01.w;   // ko+1
            o1v.x = e2.x + a23.x;  o1v.y = e2.z + a23.y;   // ko+2
            o1v.z = e3.x + a23.z;  o1v.w = e3.z + a23.w;   // ko+3
            float* dst = out + ((size_t)b * SOUT + ko) * 2;
            *reinterpret_cast<float4*>(dst)     = o0v;
            *reinterpret_cast<float4*>(dst + 4) = o1v;
        }
    }
}

extern "C" void kernel_launch(void* const* d_in, const int* in_sizes, int n_in,
                              void* d_out, int out_size, void* d_ws, size_t ws_size,
                              hipStream_t stream) {
    const float* Er = (const float*)d_in[0];
    const float* Ei = (const float*)d_in[1];
    const float* Cr = (const float*)d_in[2];   // [4, 449], row 0 used
    const float* Ci = (const float*)d_in[3];
    float* out = (float*)d_out;                // [8, 16284, 2] float32 (Re)

    dim3 grid((SOUT + NOUT - 1) / NOUT, 8);
    pbc_kernel<<<grid, BLK, 0, stream>>>(Er, Ei, Cr, Ci, out);
}